// Round 16
// baseline (230.649 us; speedup 1.0000x reference)
//
#include <hip/hip_runtime.h>
#include <math.h>

#define NB     2
#define SEQ    2048
#define NHEAD  12
#define DMODEL 768
#define SPAN2  1024
#define SCALEF 0.07216878364870323f   // 1/sqrt(192)

typedef unsigned short ushort;
typedef unsigned int   uint;
typedef __attribute__((ext_vector_type(8))) short  bh8;   // 8 x bf16
typedef __attribute__((ext_vector_type(4))) float  f32x4; // MFMA C/D frag
typedef __attribute__((ext_vector_type(4))) unsigned short us4;

__device__ inline ushort f2bf(float x) {            // RNE f32 -> bf16
    uint u = __builtin_bit_cast(uint, x);
    u += 0x7FFFu + ((u >> 16) & 1u);
    return (ushort)(u >> 16);
}
__device__ inline float b2f(ushort h) {
    uint u = ((uint)h) << 16;
    return __builtin_bit_cast(float, u);
}

// async global->LDS, 16B per lane; LDS dest = wave-uniform base + lane*16
__device__ __forceinline__ void gld16(const ushort* g, ushort* l) {
    __builtin_amdgcn_global_load_lds(
        (const __attribute__((address_space(1))) void*)g,
        (__attribute__((address_space(3))) void*)l, 16, 0, 0);
}

// swizzled b128 LDS fragment read: tile rows of 128B, 16B slots, slot^=(row&7)
__device__ __forceinline__ bh8 ldsfrag(const ushort* tile, int row, int slot) {
    return *(const bh8*)((const char*)tile + row * 128 + (((slot ^ (row & 7)) << 4)));
}

// ---------------------------------------------------------------------------
// Multi-segment f32 -> bf16 convert.
// ---------------------------------------------------------------------------
struct CvtArgs {
    const float* src[8];
    ushort*      dst[8];
    int          n[8];
};

__global__ __launch_bounds__(256) void cvt_bf16(CvtArgs a)
{
    const int seg = blockIdx.y;
    const int i   = (blockIdx.x * 256 + threadIdx.x) * 8;
    if (i >= a.n[seg]) return;
    const float4* s = (const float4*)(a.src[seg] + i);
    const float4 x = s[0], y = s[1];
    bh8 o;
    o[0] = (short)f2bf(x.x); o[1] = (short)f2bf(x.y);
    o[2] = (short)f2bf(x.z); o[3] = (short)f2bf(x.w);
    o[4] = (short)f2bf(y.x); o[5] = (short)f2bf(y.y);
    o[6] = (short)f2bf(y.z); o[7] = (short)f2bf(y.w);
    *(bh8*)(a.dst[seg] + i) = o;
}

// ---------------------------------------------------------------------------
// Merged Q/K/V projection, 64-row tiles. Grid (NB*SEQ/64, 12) = 768.
// ---------------------------------------------------------------------------
__global__ __launch_bounds__(256) void proj_qkv(
    const ushort* __restrict__ X,
    const ushort* __restrict__ Wq, const ushort* __restrict__ Wk,
    const ushort* __restrict__ Wv,
    const float* __restrict__ bq, const float* __restrict__ rwb,
    const float* __restrict__ bv,
    ushort* __restrict__ qh, ushort* __restrict__ kh, ushort* __restrict__ vht)
{
    __shared__ ushort Xs [64 * 64];
    __shared__ ushort Wqs[64 * 64];
    __shared__ ushort Wks[64 * 64];
    __shared__ ushort Wvs[64 * 64];
    const int r0 = blockIdx.x * 64;
    const int n  = blockIdx.y;
    const int c0 = n * 64;
    const int tid  = threadIdx.x;
    const int w    = tid >> 6;
    const int lane = tid & 63;
    const int lo   = lane & 15;
    const int hi8  = (lane >> 4) * 8;
    const int g4   = (lane >> 4) * 4;
    const int w16  = w * 16;
    const int r8   = lane >> 3;
    const int sl   = lane & 7;
    const int slotA = hi8 >> 3;

    f32x4 aq[4] = {}, ak[4] = {}, av[4] = {};
    for (int k0 = 0; k0 < DMODEL; k0 += 64) {
        #pragma unroll
        for (int i = 0; i < 2; ++i) {
            const int c = i * 4 + w;
            const int r = c * 8 + r8;
            const int s = sl ^ (r & 7);
            gld16(X  + (size_t)(r0 + r) * DMODEL + k0 + s * 8, Xs  + c * 512);
            gld16(Wq + (size_t)(c0 + r) * DMODEL + k0 + s * 8, Wqs + c * 512);
            gld16(Wk + (size_t)(c0 + r) * DMODEL + k0 + s * 8, Wks + c * 512);
            gld16(Wv + (size_t)(c0 + r) * DMODEL + k0 + s * 8, Wvs + c * 512);
        }
        __syncthreads();
        const bh8 a0 = ldsfrag(Xs, w16 + lo, slotA);
        const bh8 a1 = ldsfrag(Xs, w16 + lo, 4 + slotA);
        #pragma unroll
        for (int ct = 0; ct < 4; ++ct) {
            const int row = ct * 16 + lo;
            aq[ct] = __builtin_amdgcn_mfma_f32_16x16x32_bf16(a0, ldsfrag(Wqs, row, slotA),     aq[ct], 0, 0, 0);
            aq[ct] = __builtin_amdgcn_mfma_f32_16x16x32_bf16(a1, ldsfrag(Wqs, row, 4 + slotA), aq[ct], 0, 0, 0);
            ak[ct] = __builtin_amdgcn_mfma_f32_16x16x32_bf16(a0, ldsfrag(Wks, row, slotA),     ak[ct], 0, 0, 0);
            ak[ct] = __builtin_amdgcn_mfma_f32_16x16x32_bf16(a1, ldsfrag(Wks, row, 4 + slotA), ak[ct], 0, 0, 0);
            av[ct] = __builtin_amdgcn_mfma_f32_16x16x32_bf16(a0, ldsfrag(Wvs, row, slotA),     av[ct], 0, 0, 0);
            av[ct] = __builtin_amdgcn_mfma_f32_16x16x32_bf16(a1, ldsfrag(Wvs, row, 4 + slotA), av[ct], 0, 0, 0);
        }
        __syncthreads();
    }

    const int rbase = r0 + w16 + g4;
    const int bb  = rbase >> 11;           // /SEQ
    const int rr0 = rbase & (SEQ - 1);
    #pragma unroll
    for (int ct = 0; ct < 4; ++ct) {
        const int d = ct * 16 + lo;
        const int c = c0 + d;
        const float bqv = bq[c] + rwb[c];
        const float bvv = bv[c];
        us4 o;
        #pragma unroll
        for (int reg = 0; reg < 4; ++reg) {
            const size_t rowi = ((size_t)bb * NHEAD + n) * SEQ + rr0 + reg;
            qh[rowi * 64 + d] = f2bf((aq[ct][reg] + bqv) * SCALEF);
            kh[rowi * 64 + d] = f2bf(ak[ct][reg]);
            o[reg] = f2bf(av[ct][reg] + bvv);
        }
        *(us4*)&vht[(((size_t)bb * NHEAD + n) * 64 + d) * SEQ + rr0] = o;
    }
}

// ---------------------------------------------------------------------------
// Merged pos projections (unchanged).
// ---------------------------------------------------------------------------
__global__ __launch_bounds__(256) void proj_pos(
    const ushort* __restrict__ PKe, const ushort* __restrict__ PQe,
    const ushort* __restrict__ Wpk, const ushort* __restrict__ Wpq,
    const float* __restrict__ bpq,
    ushort* __restrict__ pkp, ushort* __restrict__ pqp)
{
    __shared__ ushort Xk [32 * 64];
    __shared__ ushort Xq [32 * 64];
    __shared__ ushort Wks[64 * 64];
    __shared__ ushort Wqs[64 * 64];
    const int r0 = blockIdx.x * 32;
    const int n  = blockIdx.y;
    const int c0 = n * 64;
    const int tid  = threadIdx.x;
    const int w    = tid >> 6;
    const int lane = tid & 63;
    const int lo   = lane & 15;
    const int hi8  = (lane >> 4) * 8;
    const int g4   = (lane >> 4) * 4;
    const int wr   = w & 1;
    const int wc   = w >> 1;
    const int r8   = lane >> 3;
    const int sl   = lane & 7;
    const int slotA = hi8 >> 3;

    f32x4 apk[2] = {}, apq[2] = {};
    for (int k0 = 0; k0 < DMODEL; k0 += 64) {
        {
            const int r = w * 8 + r8;
            const int s = sl ^ (r & 7);
            gld16(PKe + (size_t)(r0 + r) * DMODEL + k0 + s * 8, Xk + w * 512);
            gld16(PQe + (size_t)(r0 + r) * DMODEL + k0 + s * 8, Xq + w * 512);
        }
        #pragma unroll
        for (int i = 0; i < 2; ++i) {
            const int c = i * 4 + w;
            const int r = c * 8 + r8;
            const int s = sl ^ (r & 7);
            gld16(Wpk + (size_t)(c0 + r) * DMODEL + k0 + s * 8, Wks + c * 512);
            gld16(Wpq + (size_t)(c0 + r) * DMODEL + k0 + s * 8, Wqs + c * 512);
        }
        __syncthreads();
        const bh8 xk0 = ldsfrag(Xk, wr * 16 + lo, slotA);
        const bh8 xk1 = ldsfrag(Xk, wr * 16 + lo, 4 + slotA);
        const bh8 xq0 = ldsfrag(Xq, wr * 16 + lo, slotA);
        const bh8 xq1 = ldsfrag(Xq, wr * 16 + lo, 4 + slotA);
        #pragma unroll
        for (int ct = 0; ct < 2; ++ct) {
            const int row = wc * 32 + ct * 16 + lo;
            apk[ct] = __builtin_amdgcn_mfma_f32_16x16x32_bf16(xk0, ldsfrag(Wks, row, slotA),     apk[ct], 0, 0, 0);
            apk[ct] = __builtin_amdgcn_mfma_f32_16x16x32_bf16(xk1, ldsfrag(Wks, row, 4 + slotA), apk[ct], 0, 0, 0);
            apq[ct] = __builtin_amdgcn_mfma_f32_16x16x32_bf16(xq0, ldsfrag(Wqs, row, slotA),     apq[ct], 0, 0, 0);
            apq[ct] = __builtin_amdgcn_mfma_f32_16x16x32_bf16(xq1, ldsfrag(Wqs, row, 4 + slotA), apq[ct], 0, 0, 0);
        }
        __syncthreads();
    }

    const int rr0 = r0 + wr * 16 + g4;
    #pragma unroll
    for (int ct = 0; ct < 2; ++ct) {
        const int d = wc * 32 + ct * 16 + lo;
        const int c = c0 + d;
        const float badd = bpq[c];
        #pragma unroll
        for (int reg = 0; reg < 4; ++reg) {
            const size_t rowi = ((size_t)n * SPAN2 + rr0 + reg);
            pkp[rowi * 64 + d] = f2bf(apk[ct][reg]);
            pqp[rowi * 64 + d] = f2bf((apq[ct][reg] + badd) * SCALEF);
        }
    }
}

// ---------------------------------------------------------------------------
// Clamp-edge C/D vectors (unchanged).
// ---------------------------------------------------------------------------
__global__ __launch_bounds__(256) void cd_vec(
    const ushort* __restrict__ qh, const ushort* __restrict__ kh,
    const ushort* __restrict__ posk, const ushort* __restrict__ posq,
    float* __restrict__ cdv)
{
    __shared__ float pr[4][64];
    const int bn = blockIdx.y;
    const int n  = bn % NHEAD;
    const int tid = threadIdx.x;
    if (tid < 64) {
        pr[0][tid] = b2f(posk[((size_t)n * SPAN2) * 64 + tid]);
        pr[1][tid] = b2f(posk[((size_t)n * SPAN2 + SPAN2 - 1) * 64 + tid]);
        pr[2][tid] = b2f(posq[((size_t)n * SPAN2) * 64 + tid]);
        pr[3][tid] = b2f(posq[((size_t)n * SPAN2 + SPAN2 - 1) * 64 + tid]);
    }
    __syncthreads();
    const int row = blockIdx.x * 32 + (tid >> 3);
    const int e0  = (tid & 7) * 8;
    const bh8 q8 = *(const bh8*)&qh[((size_t)bn * SEQ + row) * 64 + e0];
    const bh8 k8 = *(const bh8*)&kh[((size_t)bn * SEQ + row) * 64 + e0];
    float a0 = 0.f, a1 = 0.f, a2 = 0.f, a3 = 0.f;
    #pragma unroll
    for (int t = 0; t < 8; ++t) {
        const float qv = b2f((ushort)q8[t]);
        const float kv = b2f((ushort)k8[t]);
        a0 += qv * pr[0][e0 + t];
        a1 += qv * pr[1][e0 + t];
        a2 += kv * pr[2][e0 + t];
        a3 += kv * pr[3][e0 + t];
    }
    #pragma unroll
    for (int off = 1; off <= 4; off <<= 1) {
        a0 += __shfl_xor(a0, off);
        a1 += __shfl_xor(a1, off);
        a2 += __shfl_xor(a2, off);
        a3 += __shfl_xor(a3, off);
    }
    if ((tid & 7) == 0) {
        cdv[((size_t)0 * NB * NHEAD + bn) * SEQ + row] = a0;
        cdv[((size_t)1 * NB * NHEAD + bn) * SEQ + row] = a1;
        cdv[((size_t)2 * NB * NHEAD + bn) * SEQ + row] = a2;
        cdv[((size_t)3 * NB * NHEAD + bn) * SEQ + row] = a3;
    }
}

// ---------------------------------------------------------------------------
// Fused MFMA flash attention v13 = v10 banded path verbatim + PAIRED clamped
// chunks: two adjacent clamped j-chunks share one staging drain (second K/V
// pair staged into the otherwise-idle POS buffer; P moved to the idle T1c,
// wave-private so reused for both chunks without an extra barrier).
// ---------------------------------------------------------------------------
__global__ __launch_bounds__(256, 3) void attn_mfma13(
    const ushort* __restrict__ qh, const ushort* __restrict__ kh,
    const ushort* __restrict__ vht, const ushort* __restrict__ posk,
    const ushort* __restrict__ posq, const float* __restrict__ mask,
    const float* __restrict__ cdv, float* __restrict__ attn)
{
    __shared__ ushort POS[128 * 64];     // banded: PK/PQ stage + P alias
                                         // clamped pair: K2 (8KB) + V2 (8KB)
    __shared__ ushort Kb [64 * 64];      // 8KB  K chunk
    __shared__ ushort Vb [64 * 64];      // 8KB  V^T chunk
    __shared__ ushort T1c[64 * 68];      // banded: [il][63-jl]; clamped: P
    __shared__ ushort T2c[64 * 68];      // banded: [jl][il]

    const int id   = blockIdx.x;          // 0..767, bn-clustered XCD swizzle
    const int xcd  = id & 7;
    const int slot = id >> 3;
    const int bn   = xcd * 3 + (slot >> 5);
    const int i0   = (slot & 31) * 64;
    const int b    = bn / NHEAD;
    const int n    = bn % NHEAD;

    const int tid  = threadIdx.x;
    const int w    = tid >> 6;
    const int lane = tid & 63;
    const int lo   = lane & 15;
    const int hi8  = (lane >> 4) * 8;
    const int g4   = (lane >> 4) * 4;
    const int w16  = w * 16;
    const int r8   = lane >> 3;
    const int sl   = lane & 7;
    const int slotA = hi8 >> 3;           // 0..3

    const ushort* qrow = qh + ((size_t)bn * SEQ + i0 + w16 + lo) * 64;
    const bh8 qa0 = *(const bh8*)&qrow[hi8];
    const bh8 qa1 = *(const bh8*)&qrow[32 + hi8];

    const ushort* khb = kh   + (size_t)bn * SEQ * 64;
    const ushort* vtb = vht  + (size_t)bn * 64 * SEQ;
    const ushort* pkh = posk + (size_t)n * SPAN2 * 64;
    const ushort* pqh = posq + (size_t)n * SPAN2 * 64;
    const float*  mrw = mask + (size_t)b * SEQ;

    float C0r[4], C1r[4];
    {
        const float* C0p = cdv + (size_t)bn * SEQ;
        const float* C1p = cdv + ((size_t)NB * NHEAD + bn) * SEQ;
        #pragma unroll
        for (int reg = 0; reg < 4; ++reg) {
            C0r[reg] = C0p[i0 + w16 + g4 + reg];
            C1r[reg] = C1p[i0 + w16 + g4 + reg];
        }
    }
    const float* D0p = cdv + ((size_t)2 * NB * NHEAD + bn) * SEQ;
    const float* D1p = cdv + ((size_t)3 * NB * NHEAD + bn) * SEQ;

    f32x4 accPV[4] = {};
    float mrow[4] = {-1e30f, -1e30f, -1e30f, -1e30f};
    float lrow[4] = {0.f, 0.f, 0.f, 0.f};

    int j0 = 0;
    while (j0 < SEQ) {
        const int d0base = i0 - j0 + 449;          // band row at u=0
        const bool clamp0 = (d0base <= -126);      // delta == 0 everywhere
        const bool clamp1 = (d0base >= 1023);      // delta == 1023 everywhere

        if (!clamp0 && !clamp1) {
        // ================= BANDED CHUNK (v10 path, verbatim) ================
        #pragma unroll
        for (int i = 0; i < 2; ++i) {
            const int c = i * 4 + w;
            const int r = c * 8 + r8;
            const int s = sl ^ (r & 7);
            gld16(khb + (size_t)(j0 + r) * 64 + s * 8, Kb + c * 512);
        }
        #pragma unroll
        for (int i = 0; i < 4; ++i) {
            const int c = i * 4 + w;
            const int r = c * 8 + r8;              // 0..127
            const int s = sl ^ (r & 7);
            int gr = d0base + r; gr = gr < 0 ? 0 : (gr > SPAN2 - 1 ? SPAN2 - 1 : gr);
            gld16(pkh + (size_t)gr * 64 + s * 8, POS + c * 512);
        }
        __syncthreads();   // B1

        const bh8 ka0 = ldsfrag(Kb, w16 + lo, slotA);
        const bh8 ka1 = ldsfrag(Kb, w16 + lo, 4 + slotA);
        f32x4 z1[5];
        #pragma unroll
        for (int q = 0; q < 5; ++q) {
            const int u1 = (w + q) * 16 + lo;      // [w16, w16+80)
            const bh8 pk0 = ldsfrag(POS, u1, slotA);
            const bh8 pk1 = ldsfrag(POS, u1, 4 + slotA);
            f32x4 a = {};
            a = __builtin_amdgcn_mfma_f32_16x16x32_bf16(qa0, pk0, a, 0, 0, 0);
            z1[q] = __builtin_amdgcn_mfma_f32_16x16x32_bf16(qa1, pk1, a, 0, 0, 0);
        }
        __syncthreads();   // B2: all POS (posk) reads done

        #pragma unroll
        for (int i = 0; i < 4; ++i) {
            const int c = i * 4 + w;
            const int r = c * 8 + r8;
            const int s = sl ^ (r & 7);
            int gr = d0base + r; gr = gr < 0 ? 0 : (gr > SPAN2 - 1 ? SPAN2 - 1 : gr);
            gld16(pqh + (size_t)gr * 64 + s * 8, POS + c * 512);
        }
        #pragma unroll
        for (int i = 0; i < 2; ++i) {
            const int c = i * 4 + w;
            const int r = c * 8 + r8;              // d row 0..63
            const int s = sl ^ (r & 7);
            gld16(vtb + (size_t)r * SEQ + j0 + s * 8, Vb + c * 512);
        }
        #pragma unroll
        for (int q = 0; q < 5; ++q)
            #pragma unroll
            for (int reg = 0; reg < 4; ++reg) {
                const int cc2 = q * 16 + lo - g4 - reg;
                if (cc2 >= 0 && cc2 < 64)
                    T1c[(w16 + g4 + reg) * 68 + cc2] = f2bf(z1[q][reg]);
            }
        f32x4 accS[4];
        #pragma unroll
        for (int ct = 0; ct < 4; ++ct) {
            const bh8 kb0 = ldsfrag(Kb, ct * 16 + lo, slotA);
            const bh8 kb1 = ldsfrag(Kb, ct * 16 + lo, 4 + slotA);
            f32x4 z = {};
            z = __builtin_amdgcn_mfma_f32_16x16x32_bf16(qa0, kb0, z, 0, 0, 0);
            accS[ct] = __builtin_amdgcn_mfma_f32_16x16x32_bf16(qa1, kb1, z, 0, 0, 0);
        }
        float maskadd[4];
        #pragma unroll
        for (int ct = 0; ct < 4; ++ct)
            maskadd[ct] = -1e6f * (1.f - mrw[j0 + ct * 16 + lo]);
        __syncthreads();   // B3: posq staged, T1c visible

        #pragma unroll
        for (int q = 0; q < 5; ++q) {
            const int u2 = (3 - w + q) * 16 + lo;  // [48-w16, 128-w16)
            const bh8 pq0 = ldsfrag(POS, u2, slotA);
            const bh8 pq1 = ldsfrag(POS, u2, 4 + slotA);
            f32x4 z = {};
            z = __builtin_amdgcn_mfma_f32_16x16x32_bf16(ka0, pq0, z, 0, 0, 0);
            z = __builtin_amdgcn_mfma_f32_16x16x32_bf16(ka1, pq1, z, 0, 0, 0);
            #pragma unroll
            for (int reg = 0; reg < 4; ++reg) {
                const int il2 = q * 16 + lo + g4 + reg - 15;
                if (il2 >= 0 && il2 < 64)
                    T2c[(w16 + g4 + reg) * 68 + il2] = f2bf(z[reg]);
            }
        }
        __syncthreads();   // B4: T2c visible; V^T staged; POS dead

        float corr[4];
        char* pbase = (char*)POS + w * 2048;
        #pragma unroll
        for (int reg = 0; reg < 4; ++reg) {
            const int il = w16 + g4 + reg;
            const int gi = i0 + il;
            float s[4], rmax = -1e30f;
            #pragma unroll
            for (int ct = 0; ct < 4; ++ct) {
                const int jl = ct * 16 + lo;
                float v = accS[ct][reg];
                if (gi >= 1 && (j0 + jl) >= 1)
                    v += b2f(T1c[il * 68 + 63 - jl]) + b2f(T2c[jl * 68 + il]);
                v += maskadd[ct];
                s[ct] = v;
                rmax = fmaxf(rmax, v);
            }
            rmax = fmaxf(rmax, __shfl_xor(rmax, 1));
            rmax = fmaxf(rmax, __shfl_xor(rmax, 2));
            rmax = fmaxf(rmax, __shfl_xor(rmax, 4));
            rmax = fmaxf(rmax, __shfl_xor(rmax, 8));
            const float mnew = fmaxf(mrow[reg], rmax);
            const float cc   = __expf(mrow[reg] - mnew);
            float psum = 0.f;
            const int prow = g4 + reg;
            #pragma unroll
            for (int ct = 0; ct < 4; ++ct) {
                const float p = __expf(s[ct] - mnew);
                psum += p;
                *(ushort*)(pbase + prow * 128 + ((((ct * 16 + lo) * 2)) ^ ((prow & 7) * 16))) = f2bf(p);
            }
            psum += __shfl_xor(psum, 1);
            psum += __shfl_xor(psum, 2);
            psum += __shfl_xor(psum, 4);
            psum += __shfl_xor(psum, 8);
            lrow[reg] = lrow[reg] * cc + psum;
            mrow[reg] = mnew;
            corr[reg] = cc;
        }

        {
            const bh8 pa0 = *(const bh8*)(pbase + lo * 128 + ((slotA << 4) ^ ((lo & 7) * 16)));
            const bh8 pa1 = *(const bh8*)(pbase + lo * 128 + (((4 + slotA) << 4) ^ ((lo & 7) * 16)));
            #pragma unroll
            for (int dt = 0; dt < 4; ++dt) {
                const bh8 vb0 = ldsfrag(Vb, dt * 16 + lo, slotA);
                const bh8 vb1 = ldsfrag(Vb, dt * 16 + lo, 4 + slotA);
                f32x4 a = accPV[dt];
                #pragma unroll
                for (int reg = 0; reg < 4; ++reg) a[reg] *= corr[reg];
                a = __builtin_amdgcn_mfma_f32_16x16x32_bf16(pa0, vb0, a, 0, 0, 0);
                accPV[dt] = __builtin_amdgcn_mfma_f32_16x16x32_bf16(pa1, vb1, a, 0, 0, 0);
            }
        }
        __syncthreads();   // B5
        j0 += 64;

        } else {
        // ================= CLAMPED CHUNK(S) — PAIRED when possible ==========
        const int j0B = j0 + 64;
        bool clamp0B = false, clamp1B = false;
        if (j0B < SEQ) {
            const int dB = i0 - j0B + 449;
            clamp0B = (dB <= -126);
            clamp1B = (dB >= 1023);
        }
        const bool pairB = clamp0B || clamp1B;

        // ---- stage chunk A -> Kb/Vb, chunk B -> POS halves; ONE drain ----
        #pragma unroll
        for (int i = 0; i < 2; ++i) {
            const int c = i * 4 + w;
            const int r = c * 8 + r8;
            const int s = sl ^ (r & 7);
            gld16(khb + (size_t)(j0 + r) * 64 + s * 8, Kb + c * 512);
            gld16(vtb + (size_t)r * SEQ + j0 + s * 8, Vb + c * 512);
        }
        if (pairB) {
            #pragma unroll
            for (int i = 0; i < 2; ++i) {
                const int c = i * 4 + w;
                const int r = c * 8 + r8;
                const int s = sl ^ (r & 7);
                gld16(khb + (size_t)(j0B + r) * 64 + s * 8, POS + c * 512);
                gld16(vtb + (size_t)r * SEQ + j0B + s * 8, POS + 4096 + c * 512);
            }
        }
        __syncthreads();   // CB1: single drain for 1 or 2 chunks

        char* pbase = (char*)T1c + w * 2048;   // P lives in idle T1c

        // ---------------- chunk A ----------------
        {
            const float* Dp = clamp0 ? D0p : D1p;
            float Dvv[4], maskadd[4];
            #pragma unroll
            for (int ct = 0; ct < 4; ++ct) {
                Dvv[ct]     = Dp[j0 + ct * 16 + lo];
                maskadd[ct] = -1e6f * (1.f - mrw[j0 + ct * 16 + lo]);
            }
            f32x4 accS[4];
            #pragma unroll
            for (int ct = 0; ct < 4; ++ct) {
                const bh8 kb0 = ldsfrag(Kb, ct * 16 + lo, slotA);
                const bh8 kb1 = ldsfrag(Kb, ct * 16 + lo, 4 + slotA);
                f32x4 z = {};
                z = __builtin_amdgcn_mfma_f32_16x16x32_bf16(qa0, kb0, z, 0, 0, 0);
                accS[ct] = __builtin_amdgcn_mfma_f32_16x16x32_bf16(qa1, kb1, z, 0, 0, 0);
            }
            float corr[4];
            #pragma unroll
            for (int reg = 0; reg < 4; ++reg) {
                const int il = w16 + g4 + reg;
                const int gi = i0 + il;
                const float Cvv = clamp0 ? C0r[reg] : C1r[reg];
                float s[4], rmax = -1e30f;
                #pragma unroll
                for (int ct = 0; ct < 4; ++ct) {
                    const int jl = ct * 16 + lo;
                    float v = accS[ct][reg];
                    if (gi >= 1 && (j0 + jl) >= 1)
                        v += Cvv + Dvv[ct];
                    v += maskadd[ct];
                    s[ct] = v;
                    rmax = fmaxf(rmax, v);
                }
                rmax = fmaxf(rmax, __shfl_xor(rmax, 1));
                rmax = fmaxf(rmax, __shfl_xor(rmax, 2));
                rmax = fmaxf(rmax, __shfl_xor(rmax, 4));
                rmax = fmaxf(rmax, __shfl_xor(rmax, 8));
                const float mnew = fmaxf(mrow[reg], rmax);
                const float cc   = __expf(mrow[reg] - mnew);
                float psum = 0.f;
                const int prow = g4 + reg;
                #pragma unroll
                for (int ct = 0; ct < 4; ++ct) {
                    const float p = __expf(s[ct] - mnew);
                    psum += p;
                    *(ushort*)(pbase + prow * 128 + ((((ct * 16 + lo) * 2)) ^ ((prow & 7) * 16))) = f2bf(p);
                }
                psum += __shfl_xor(psum, 1);
                psum += __shfl_xor(psum, 2);
                psum += __shfl_xor(psum, 4);
                psum += __shfl_xor(psum, 8);
                lrow[reg] = lrow[reg] * cc + psum;
                mrow[reg] = mnew;
                corr[reg] = cc;
            }
            const bh8 pa0 = *(const bh8*)(pbase + lo * 128 + ((slotA << 4) ^ ((lo & 7) * 16)));
            const bh8 pa1 = *(const bh8*)(pbase + lo * 128 + (((4 + slotA) << 4) ^ ((lo & 7) * 16)));
            #pragma unroll
            for (int dt = 0; dt < 4; ++dt) {
                const bh8 vb0 = ldsfrag(Vb, dt * 16 + lo, slotA);
                const bh8 vb1 = ldsfrag(Vb, dt * 16 + lo, 4 + slotA);
                f32x4 a = accPV[dt];
                #pragma unroll
                for (int reg = 0; reg < 4; ++reg) a[reg] *= corr[reg];
                a = __builtin_amdgcn_mfma_f32_16x16x32_bf16(pa0, vb0, a, 0, 0, 0);
                accPV[dt] = __builtin_amdgcn_mfma_f32_16x16x32_bf16(pa1, vb1, a, 0, 0, 0);
            }
        }

        // ---------------- chunk B (from POS halves; P region reused) -------
        if (pairB) {
            const ushort* Kb2 = POS;
            const ushort* Vb2 = POS + 4096;
            const float* Dp = clamp0B ? D0p : D1p;
            float Dvv[4], maskadd[4];
            #pragma unroll
            for (int ct = 0; ct < 4; ++ct) {
                Dvv[ct]     = Dp[j0B + ct * 16 + lo];
                maskadd[ct] = -1e6f * (1.f - mrw[j0B + ct * 16 + lo]);
            }
            f32x4 accS[4];
            #pragma unroll
            for (int ct = 0; ct < 4; ++ct) {
                const bh8 kb0 = ldsfrag(Kb2, ct * 16 + lo, slotA);
                const bh8 kb1 = ldsfrag(Kb2, ct * 16 + lo, 4 + slotA);
                f32x4 z = {};
                z = __builtin_amdgcn_mfma_f32_16x16x32_bf16(qa0, kb0, z, 0, 0, 0);
                accS[ct] = __builtin_amdgcn_mfma_f32_16x16x32_bf16(qa1, kb1, z, 0, 0, 0);
            }
            float corr[4];
            #pragma unroll
            for (int reg = 0; reg < 4; ++reg) {
                const int il = w16 + g4 + reg;
                const int gi = i0 + il;
                const float Cvv = clamp0B ? C0r[reg] : C1r[reg];
                float s[4], rmax = -1e30f;
                #pragma unroll
                for (int ct = 0; ct < 4; ++ct) {
                    const int jl = ct * 16 + lo;
                    float v = accS[ct][reg];
                    if (gi >= 1 && (j0B + jl) >= 1)
                        v += Cvv + Dvv[ct];
                    v += maskadd[ct];
                    s[ct] = v;
                    rmax = fmaxf(rmax, v);
                }
                rmax = fmaxf(rmax, __shfl_xor(rmax, 1));
                rmax = fmaxf(rmax, __shfl_xor(rmax, 2));
                rmax = fmaxf(rmax, __shfl_xor(rmax, 4));
                rmax = fmaxf(rmax, __shfl_xor(rmax, 8));
                const float mnew = fmaxf(mrow[reg], rmax);
                const float cc   = __expf(mrow[reg] - mnew);
                float psum = 0.f;
                const int prow = g4 + reg;
                #pragma unroll
                for (int ct = 0; ct < 4; ++ct) {
                    const float p = __expf(s[ct] - mnew);
                    psum += p;
                    *(ushort*)(pbase + prow * 128 + ((((ct * 16 + lo) * 2)) ^ ((prow & 7) * 16))) = f2bf(p);
                }
                psum += __shfl_xor(psum, 1);
                psum += __shfl_xor(psum, 2);
                psum += __shfl_xor(psum, 4);
                psum += __shfl_xor(psum, 8);
                lrow[reg] = lrow[reg] * cc + psum;
                mrow[reg] = mnew;
                corr[reg] = cc;
            }
            const bh8 pa0 = *(const bh8*)(pbase + lo * 128 + ((slotA << 4) ^ ((lo & 7) * 16)));
            const bh8 pa1 = *(const bh8*)(pbase + lo * 128 + (((4 + slotA) << 4) ^ ((lo & 7) * 16)));
            #pragma unroll
            for (int dt = 0; dt < 4; ++dt) {
                const bh8 vb0 = ldsfrag(Vb2, dt * 16 + lo, slotA);
                const bh8 vb1 = ldsfrag(Vb2, dt * 16 + lo, 4 + slotA);
                f32x4 a = accPV[dt];
                #pragma unroll
                for (int reg = 0; reg < 4; ++reg) a[reg] *= corr[reg];
                a = __builtin_amdgcn_mfma_f32_16x16x32_bf16(pa0, vb0, a, 0, 0, 0);
                accPV[dt] = __builtin_amdgcn_mfma_f32_16x16x32_bf16(pa1, vb1, a, 0, 0, 0);
            }
        }
        __syncthreads();   // CB2
        j0 += pairB ? 128 : 64;
        }
    }

    #pragma unroll
    for (int reg = 0; reg < 4; ++reg) {
        const int i = i0 + w16 + g4 + reg;
        const float inv = 1.f / lrow[reg];
        #pragma unroll
        for (int dt = 0; dt < 4; ++dt)
            attn[((size_t)b * SEQ + i) * DMODEL + n * 64 + dt * 16 + lo] =
                accPV[dt][reg] * inv;
    }
}

// ---------------------------------------------------------------------------
// Residual + LayerNorm, in-place on attn buffer.
// ---------------------------------------------------------------------------
__global__ __launch_bounds__(256) void resid_ln(
    float* __restrict__ attn, const float* __restrict__ query,
    const float* __restrict__ gamma, const float* __restrict__ beta)
{
    const int b = blockIdx.y;
    const int i = blockIdx.x;
    const size_t base = ((size_t)b * SEQ + i) * DMODEL;
    const int tid = threadIdx.x;

    float x[3];
    #pragma unroll
    for (int s = 0; s < 3; ++s) x[s] = attn[base + s * 256 + tid];

    float sum = x[0] + x[1] + x[2];
    float sq  = x[0]*x[0] + x[1]*x[1] + x[2]*x[2];
    #pragma unroll
    for (int off = 32; off; off >>= 1) {
        sum += __shfl_xor(sum, off);
        sq  += __shfl_xor(sq, off);
    }
    __shared__ float red[2][4];
    const int w = tid >> 6;
    if ((tid & 63) == 0) { red[0][w] = sum; red[1][w] = sq; }
    __syncthreads();
    sum = red[0][0] + red[0][1] + red[0][2] + red[0][3];
    sq  = red[1][0] + red[1][1] + red[1][2] + red[1][3];

    const float mu  = sum * (1.f / DMODEL);
    const float var = sq * (1.f / DMODEL) - mu * mu;
    const float inv = rsqrtf(var + 1e-5f);

    #pragma unroll
    for (int s = 0; s < 3; ++s) {
        const int c = s * 256 + tid;
        attn[base + c] = query[base + c] + (x[s] - mu) * inv * gamma[c] + beta[c];
    }
}

// ---------------------------------------------------------------------------
extern "C" void kernel_launch(void* const* d_in, const int* in_sizes, int n_in,
                              void* d_out, int out_size, void* d_ws, size_t ws_size,
                              hipStream_t stream)
{
    const float* query = (const float*)d_in[0];
    const float* mask  = (const float*)d_in[1];
    const float* pke   = (const float*)d_in[2];
    const float* pqe   = (const float*)d_in[3];
    const float* Wq    = (const float*)d_in[4];
    const float* bq    = (const float*)d_in[5];
    const float* Wk    = (const float*)d_in[6];
    const float* Wv    = (const float*)d_in[7];
    const float* bv    = (const float*)d_in[8];
    const float* Wpq   = (const float*)d_in[9];
    const float* bpq   = (const float*)d_in[10];
    const float* Wpk   = (const float*)d_in[11];
    const float* rwb   = (const float*)d_in[12];
    const float* gamma = (const float*)d_in[13];
    const float* beta  = (const float*)d_in[14];

    float* out = (float*)d_out;

    const int Q_N  = NB * SEQ * DMODEL;
    const int P_N  = SPAN2 * DMODEL;
    const int W_N  = DMODEL * DMODEL;
    const size_t QKV_ELEMS = (size_t)NB * NHEAD * SEQ * 64;
    const size_t POS_ELEMS = (size_t)NHEAD * SPAN2 * 64;

    ushort* xb   = (ushort*)d_ws;
    ushort* pkeb = xb   + Q_N;
    ushort* pqeb = pkeb + P_N;
    ushort* wqb  = pqeb + P_N;
    ushort* wkb  = wqb  + W_N;
    ushort* wvb  = wkb  + W_N;
    ushort* wpqb = wvb  + W_N;
    ushort* wpkb = wpqb + W_N;
    ushort* qh   = wpkb + W_N;
    ushort* kh   = qh   + QKV_ELEMS;
    ushort* vht  = kh   + QKV_ELEMS;
    ushort* pkp  = vht  + QKV_ELEMS;
    ushort* pqp  = pkp  + POS_ELEMS;
    float*  cdv  = (float*)(pqp + POS_ELEMS);   // [4][24][2048] f32

    dim3 blk(256);

    CvtArgs ca;
    ca.src[0] = query; ca.dst[0] = xb;   ca.n[0] = Q_N;
    ca.src[1] = pke;   ca.dst[1] = pkeb; ca.n[1] = P_N;
    ca.src[2] = pqe;   ca.dst[2] = pqeb; ca.n[2] = P_N;
    ca.src[3] = Wq;    ca.dst[3] = wqb;  ca.n[3] = W_N;
    ca.src[4] = Wk;    ca.dst[4] = wkb;  ca.n[4] = W_N;
    ca.src[5] = Wv;    ca.dst[5] = wvb;  ca.n[5] = W_N;
    ca.src[6] = Wpq;   ca.dst[6] = wpqb; ca.n[6] = W_N;
    ca.src[7] = Wpk;   ca.dst[7] = wpkb; ca.n[7] = W_N;
    cvt_bf16<<<dim3((Q_N / 8 + 255) / 256, 8), blk, 0, stream>>>(ca);

    // merged projections
    proj_qkv<<<dim3(NB * SEQ / 64, NHEAD), blk, 0, stream>>>(
        xb, wqb, wkb, wvb, bq, rwb, bv, qh, kh, vht);
    proj_pos<<<dim3(SPAN2 / 32, NHEAD), blk, 0, stream>>>(
        pkeb, pqeb, wpkb, wpqb, bpq, pkp, pqp);

    // clamp-edge C/D vectors
    cd_vec<<<dim3(SEQ / 32, NB * NHEAD), blk, 0, stream>>>(
        qh, kh, pkp, pqp, cdv);

    // fused attention (v10 banded + paired clamped chunks) -> d_out
    attn_mfma13<<<dim3(NB * NHEAD * (SEQ / 64)), blk, 0, stream>>>(
        qh, kh, vht, pkp, pqp, mask, cdv, out);

    // residual + LN in-place
    resid_ln<<<dim3(SEQ, NB), blk, 0, stream>>>(out, query, gamma, beta);
}

// Round 17
// 207.382 us; speedup vs baseline: 1.1122x; 1.1122x over previous
//
#include <hip/hip_runtime.h>
#include <math.h>

#define NB     2
#define SEQ    2048
#define NHEAD  12
#define DMODEL 768
#define SPAN2  1024
#define SCALEF 0.07216878364870323f   // 1/sqrt(192)

typedef unsigned short ushort;
typedef unsigned int   uint;
typedef __attribute__((ext_vector_type(8))) short  bh8;   // 8 x bf16
typedef __attribute__((ext_vector_type(4))) float  f32x4; // MFMA C/D frag
typedef __attribute__((ext_vector_type(4))) unsigned short us4;

__device__ inline ushort f2bf(float x) {            // RNE f32 -> bf16
    uint u = __builtin_bit_cast(uint, x);
    u += 0x7FFFu + ((u >> 16) & 1u);
    return (ushort)(u >> 16);
}
__device__ inline float b2f(ushort h) {
    uint u = ((uint)h) << 16;
    return __builtin_bit_cast(float, u);
}

// async global->LDS, 16B per lane; LDS dest = wave-uniform base + lane*16
__device__ __forceinline__ void gld16(const ushort* g, ushort* l) {
    __builtin_amdgcn_global_load_lds(
        (const __attribute__((address_space(1))) void*)g,
        (__attribute__((address_space(3))) void*)l, 16, 0, 0);
}

// swizzled b128 LDS fragment read: tile rows of 128B, 16B slots, slot^=(row&7)
__device__ __forceinline__ bh8 ldsfrag(const ushort* tile, int row, int slot) {
    return *(const bh8*)((const char*)tile + row * 128 + (((slot ^ (row & 7)) << 4)));
}

// ---------------------------------------------------------------------------
// Multi-segment f32 -> bf16 convert.
// ---------------------------------------------------------------------------
struct CvtArgs {
    const float* src[8];
    ushort*      dst[8];
    int          n[8];
};

__global__ __launch_bounds__(256) void cvt_bf16(CvtArgs a)
{
    const int seg = blockIdx.y;
    const int i   = (blockIdx.x * 256 + threadIdx.x) * 8;
    if (i >= a.n[seg]) return;
    const float4* s = (const float4*)(a.src[seg] + i);
    const float4 x = s[0], y = s[1];
    bh8 o;
    o[0] = (short)f2bf(x.x); o[1] = (short)f2bf(x.y);
    o[2] = (short)f2bf(x.z); o[3] = (short)f2bf(x.w);
    o[4] = (short)f2bf(y.x); o[5] = (short)f2bf(y.y);
    o[6] = (short)f2bf(y.z); o[7] = (short)f2bf(y.w);
    *(bh8*)(a.dst[seg] + i) = o;
}

// ---------------------------------------------------------------------------
// Merged Q/K/V projection, 64-row tiles. Grid (NB*SEQ/64, 12) = 768 = 3/CU.
// ---------------------------------------------------------------------------
__global__ __launch_bounds__(256) void proj_qkv(
    const ushort* __restrict__ X,
    const ushort* __restrict__ Wq, const ushort* __restrict__ Wk,
    const ushort* __restrict__ Wv,
    const float* __restrict__ bq, const float* __restrict__ rwb,
    const float* __restrict__ bv,
    ushort* __restrict__ qh, ushort* __restrict__ kh, ushort* __restrict__ vht)
{
    __shared__ ushort Xs [64 * 64];
    __shared__ ushort Wqs[64 * 64];
    __shared__ ushort Wks[64 * 64];
    __shared__ ushort Wvs[64 * 64];
    const int r0 = blockIdx.x * 64;
    const int n  = blockIdx.y;
    const int c0 = n * 64;
    const int tid  = threadIdx.x;
    const int w    = tid >> 6;
    const int lane = tid & 63;
    const int lo   = lane & 15;
    const int hi8  = (lane >> 4) * 8;
    const int g4   = (lane >> 4) * 4;
    const int w16  = w * 16;
    const int r8   = lane >> 3;
    const int sl   = lane & 7;
    const int slotA = hi8 >> 3;

    f32x4 aq[4] = {}, ak[4] = {}, av[4] = {};
    for (int k0 = 0; k0 < DMODEL; k0 += 64) {
        #pragma unroll
        for (int i = 0; i < 2; ++i) {
            const int c = i * 4 + w;
            const int r = c * 8 + r8;
            const int s = sl ^ (r & 7);
            gld16(X  + (size_t)(r0 + r) * DMODEL + k0 + s * 8, Xs  + c * 512);
            gld16(Wq + (size_t)(c0 + r) * DMODEL + k0 + s * 8, Wqs + c * 512);
            gld16(Wk + (size_t)(c0 + r) * DMODEL + k0 + s * 8, Wks + c * 512);
            gld16(Wv + (size_t)(c0 + r) * DMODEL + k0 + s * 8, Wvs + c * 512);
        }
        __syncthreads();
        const bh8 a0 = ldsfrag(Xs, w16 + lo, slotA);
        const bh8 a1 = ldsfrag(Xs, w16 + lo, 4 + slotA);
        #pragma unroll
        for (int ct = 0; ct < 4; ++ct) {
            const int row = ct * 16 + lo;
            aq[ct] = __builtin_amdgcn_mfma_f32_16x16x32_bf16(a0, ldsfrag(Wqs, row, slotA),     aq[ct], 0, 0, 0);
            aq[ct] = __builtin_amdgcn_mfma_f32_16x16x32_bf16(a1, ldsfrag(Wqs, row, 4 + slotA), aq[ct], 0, 0, 0);
            ak[ct] = __builtin_amdgcn_mfma_f32_16x16x32_bf16(a0, ldsfrag(Wks, row, slotA),     ak[ct], 0, 0, 0);
            ak[ct] = __builtin_amdgcn_mfma_f32_16x16x32_bf16(a1, ldsfrag(Wks, row, 4 + slotA), ak[ct], 0, 0, 0);
            av[ct] = __builtin_amdgcn_mfma_f32_16x16x32_bf16(a0, ldsfrag(Wvs, row, slotA),     av[ct], 0, 0, 0);
            av[ct] = __builtin_amdgcn_mfma_f32_16x16x32_bf16(a1, ldsfrag(Wvs, row, 4 + slotA), av[ct], 0, 0, 0);
        }
        __syncthreads();
    }

    const int rbase = r0 + w16 + g4;
    const int bb  = rbase >> 11;           // /SEQ
    const int rr0 = rbase & (SEQ - 1);
    #pragma unroll
    for (int ct = 0; ct < 4; ++ct) {
        const int d = ct * 16 + lo;
        const int c = c0 + d;
        const float bqv = bq[c] + rwb[c];
        const float bvv = bv[c];
        us4 o;
        #pragma unroll
        for (int reg = 0; reg < 4; ++reg) {
            const size_t rowi = ((size_t)bb * NHEAD + n) * SEQ + rr0 + reg;
            qh[rowi * 64 + d] = f2bf((aq[ct][reg] + bqv) * SCALEF);
            kh[rowi * 64 + d] = f2bf(ak[ct][reg]);
            o[reg] = f2bf(av[ct][reg] + bvv);
        }
        *(us4*)&vht[(((size_t)bb * NHEAD + n) * 64 + d) * SEQ + rr0] = o;
    }
}

// ---------------------------------------------------------------------------
// Merged pos projections.
// ---------------------------------------------------------------------------
__global__ __launch_bounds__(256) void proj_pos(
    const ushort* __restrict__ PKe, const ushort* __restrict__ PQe,
    const ushort* __restrict__ Wpk, const ushort* __restrict__ Wpq,
    const float* __restrict__ bpq,
    ushort* __restrict__ pkp, ushort* __restrict__ pqp)
{
    __shared__ ushort Xk [32 * 64];
    __shared__ ushort Xq [32 * 64];
    __shared__ ushort Wks[64 * 64];
    __shared__ ushort Wqs[64 * 64];
    const int r0 = blockIdx.x * 32;
    const int n  = blockIdx.y;
    const int c0 = n * 64;
    const int tid  = threadIdx.x;
    const int w    = tid >> 6;
    const int lane = tid & 63;
    const int lo   = lane & 15;
    const int hi8  = (lane >> 4) * 8;
    const int g4   = (lane >> 4) * 4;
    const int wr   = w & 1;
    const int wc   = w >> 1;
    const int r8   = lane >> 3;
    const int sl   = lane & 7;
    const int slotA = hi8 >> 3;

    f32x4 apk[2] = {}, apq[2] = {};
    for (int k0 = 0; k0 < DMODEL; k0 += 64) {
        {
            const int r = w * 8 + r8;
            const int s = sl ^ (r & 7);
            gld16(PKe + (size_t)(r0 + r) * DMODEL + k0 + s * 8, Xk + w * 512);
            gld16(PQe + (size_t)(r0 + r) * DMODEL + k0 + s * 8, Xq + w * 512);
        }
        #pragma unroll
        for (int i = 0; i < 2; ++i) {
            const int c = i * 4 + w;
            const int r = c * 8 + r8;
            const int s = sl ^ (r & 7);
            gld16(Wpk + (size_t)(c0 + r) * DMODEL + k0 + s * 8, Wks + c * 512);
            gld16(Wpq + (size_t)(c0 + r) * DMODEL + k0 + s * 8, Wqs + c * 512);
        }
        __syncthreads();
        const bh8 xk0 = ldsfrag(Xk, wr * 16 + lo, slotA);
        const bh8 xk1 = ldsfrag(Xk, wr * 16 + lo, 4 + slotA);
        const bh8 xq0 = ldsfrag(Xq, wr * 16 + lo, slotA);
        const bh8 xq1 = ldsfrag(Xq, wr * 16 + lo, 4 + slotA);
        #pragma unroll
        for (int ct = 0; ct < 2; ++ct) {
            const int row = wc * 32 + ct * 16 + lo;
            apk[ct] = __builtin_amdgcn_mfma_f32_16x16x32_bf16(xk0, ldsfrag(Wks, row, slotA),     apk[ct], 0, 0, 0);
            apk[ct] = __builtin_amdgcn_mfma_f32_16x16x32_bf16(xk1, ldsfrag(Wks, row, 4 + slotA), apk[ct], 0, 0, 0);
            apq[ct] = __builtin_amdgcn_mfma_f32_16x16x32_bf16(xq0, ldsfrag(Wqs, row, slotA),     apq[ct], 0, 0, 0);
            apq[ct] = __builtin_amdgcn_mfma_f32_16x16x32_bf16(xq1, ldsfrag(Wqs, row, 4 + slotA), apq[ct], 0, 0, 0);
        }
        __syncthreads();
    }

    const int rr0 = r0 + wr * 16 + g4;
    #pragma unroll
    for (int ct = 0; ct < 2; ++ct) {
        const int d = wc * 32 + ct * 16 + lo;
        const int c = c0 + d;
        const float badd = bpq[c];
        #pragma unroll
        for (int reg = 0; reg < 4; ++reg) {
            const size_t rowi = ((size_t)n * SPAN2 + rr0 + reg);
            pkp[rowi * 64 + d] = f2bf(apk[ct][reg]);
            pqp[rowi * 64 + d] = f2bf((apq[ct][reg] + badd) * SCALEF);
        }
    }
}

// ---------------------------------------------------------------------------
// Clamp-edge C/D vectors.
// ---------------------------------------------------------------------------
__global__ __launch_bounds__(256) void cd_vec(
    const ushort* __restrict__ qh, const ushort* __restrict__ kh,
    const ushort* __restrict__ posk, const ushort* __restrict__ posq,
    float* __restrict__ cdv)
{
    __shared__ float pr[4][64];
    const int bn = blockIdx.y;
    const int n  = bn % NHEAD;
    const int tid = threadIdx.x;
    if (tid < 64) {
        pr[0][tid] = b2f(posk[((size_t)n * SPAN2) * 64 + tid]);
        pr[1][tid] = b2f(posk[((size_t)n * SPAN2 + SPAN2 - 1) * 64 + tid]);
        pr[2][tid] = b2f(posq[((size_t)n * SPAN2) * 64 + tid]);
        pr[3][tid] = b2f(posq[((size_t)n * SPAN2 + SPAN2 - 1) * 64 + tid]);
    }
    __syncthreads();
    const int row = blockIdx.x * 32 + (tid >> 3);
    const int e0  = (tid & 7) * 8;
    const bh8 q8 = *(const bh8*)&qh[((size_t)bn * SEQ + row) * 64 + e0];
    const bh8 k8 = *(const bh8*)&kh[((size_t)bn * SEQ + row) * 64 + e0];
    float a0 = 0.f, a1 = 0.f, a2 = 0.f, a3 = 0.f;
    #pragma unroll
    for (int t = 0; t < 8; ++t) {
        const float qv = b2f((ushort)q8[t]);
        const float kv = b2f((ushort)k8[t]);
        a0 += qv * pr[0][e0 + t];
        a1 += qv * pr[1][e0 + t];
        a2 += kv * pr[2][e0 + t];
        a3 += kv * pr[3][e0 + t];
    }
    #pragma unroll
    for (int off = 1; off <= 4; off <<= 1) {
        a0 += __shfl_xor(a0, off);
        a1 += __shfl_xor(a1, off);
        a2 += __shfl_xor(a2, off);
        a3 += __shfl_xor(a3, off);
    }
    if ((tid & 7) == 0) {
        cdv[((size_t)0 * NB * NHEAD + bn) * SEQ + row] = a0;
        cdv[((size_t)1 * NB * NHEAD + bn) * SEQ + row] = a1;
        cdv[((size_t)2 * NB * NHEAD + bn) * SEQ + row] = a2;
        cdv[((size_t)3 * NB * NHEAD + bn) * SEQ + row] = a3;
    }
}

// ---------------------------------------------------------------------------
// Fused MFMA flash attention v10 (best measured: 171us attn, 208us total):
// compact diagonal tables T1c/T2c, single POS buffer staged twice per chunk,
// slim clamped path from cdv. 49KB LDS -> 3 blocks/CU, grid 768 exact.
// ---------------------------------------------------------------------------
__global__ __launch_bounds__(256, 3) void attn_mfma10(
    const ushort* __restrict__ qh, const ushort* __restrict__ kh,
    const ushort* __restrict__ vht, const ushort* __restrict__ posk,
    const ushort* __restrict__ posq, const float* __restrict__ mask,
    const float* __restrict__ cdv, float* __restrict__ attn)
{
    __shared__ ushort POS[128 * 64];     // 16KB: PK stage / PQ stage / P alias
    __shared__ ushort Kb [64 * 64];      // 8KB  K chunk
    __shared__ ushort Vb [64 * 64];      // 8KB  V^T chunk
    __shared__ ushort T1c[64 * 68];      // 8.5KB  [il][63-jl]
    __shared__ ushort T2c[64 * 68];      // 8.5KB  [jl][il]

    const int id   = blockIdx.x;          // 0..767, bn-clustered XCD swizzle
    const int xcd  = id & 7;
    const int slot = id >> 3;
    const int bn   = xcd * 3 + (slot >> 5);
    const int i0   = (slot & 31) * 64;
    const int b    = bn / NHEAD;
    const int n    = bn % NHEAD;

    const int tid  = threadIdx.x;
    const int w    = tid >> 6;
    const int lane = tid & 63;
    const int lo   = lane & 15;
    const int hi8  = (lane >> 4) * 8;
    const int g4   = (lane >> 4) * 4;
    const int w16  = w * 16;
    const int r8   = lane >> 3;
    const int sl   = lane & 7;
    const int slotA = hi8 >> 3;           // 0..3

    const ushort* qrow = qh + ((size_t)bn * SEQ + i0 + w16 + lo) * 64;
    const bh8 qa0 = *(const bh8*)&qrow[hi8];
    const bh8 qa1 = *(const bh8*)&qrow[32 + hi8];

    const ushort* khb = kh   + (size_t)bn * SEQ * 64;
    const ushort* vtb = vht  + (size_t)bn * 64 * SEQ;
    const ushort* pkh = posk + (size_t)n * SPAN2 * 64;
    const ushort* pqh = posq + (size_t)n * SPAN2 * 64;
    const float*  mrw = mask + (size_t)b * SEQ;

    // hoisted clamp-edge C values for this wave's 4 rows (both edges)
    float C0r[4], C1r[4];
    {
        const float* C0p = cdv + (size_t)bn * SEQ;
        const float* C1p = cdv + ((size_t)NB * NHEAD + bn) * SEQ;
        #pragma unroll
        for (int reg = 0; reg < 4; ++reg) {
            C0r[reg] = C0p[i0 + w16 + g4 + reg];
            C1r[reg] = C1p[i0 + w16 + g4 + reg];
        }
    }
    const float* D0p = cdv + ((size_t)2 * NB * NHEAD + bn) * SEQ;
    const float* D1p = cdv + ((size_t)3 * NB * NHEAD + bn) * SEQ;

    f32x4 accPV[4] = {};
    float mrow[4] = {-1e30f, -1e30f, -1e30f, -1e30f};
    float lrow[4] = {0.f, 0.f, 0.f, 0.f};

    for (int j0 = 0; j0 < SEQ; j0 += 64) {
        const int d0base = i0 - j0 + 449;          // band row at u=0
        const bool clamp0 = (d0base <= -126);      // delta == 0 everywhere
        const bool clamp1 = (d0base >= 1023);      // delta == 1023 everywhere

        if (!clamp0 && !clamp1) {
        // ================= BANDED CHUNK =================
        #pragma unroll
        for (int i = 0; i < 2; ++i) {
            const int c = i * 4 + w;
            const int r = c * 8 + r8;
            const int s = sl ^ (r & 7);
            gld16(khb + (size_t)(j0 + r) * 64 + s * 8, Kb + c * 512);
        }
        #pragma unroll
        for (int i = 0; i < 4; ++i) {
            const int c = i * 4 + w;
            const int r = c * 8 + r8;              // 0..127
            const int s = sl ^ (r & 7);
            int gr = d0base + r; gr = gr < 0 ? 0 : (gr > SPAN2 - 1 ? SPAN2 - 1 : gr);
            gld16(pkh + (size_t)gr * 64 + s * 8, POS + c * 512);
        }
        __syncthreads();   // B1

        const bh8 ka0 = ldsfrag(Kb, w16 + lo, slotA);
        const bh8 ka1 = ldsfrag(Kb, w16 + lo, 4 + slotA);
        f32x4 z1[5];
        #pragma unroll
        for (int q = 0; q < 5; ++q) {
            const int u1 = (w + q) * 16 + lo;      // [w16, w16+80)
            const bh8 pk0 = ldsfrag(POS, u1, slotA);
            const bh8 pk1 = ldsfrag(POS, u1, 4 + slotA);
            f32x4 a = {};
            a = __builtin_amdgcn_mfma_f32_16x16x32_bf16(qa0, pk0, a, 0, 0, 0);
            z1[q] = __builtin_amdgcn_mfma_f32_16x16x32_bf16(qa1, pk1, a, 0, 0, 0);
        }
        __syncthreads();   // B2: all POS (posk) reads done

        #pragma unroll
        for (int i = 0; i < 4; ++i) {
            const int c = i * 4 + w;
            const int r = c * 8 + r8;
            const int s = sl ^ (r & 7);
            int gr = d0base + r; gr = gr < 0 ? 0 : (gr > SPAN2 - 1 ? SPAN2 - 1 : gr);
            gld16(pqh + (size_t)gr * 64 + s * 8, POS + c * 512);
        }
        #pragma unroll
        for (int i = 0; i < 2; ++i) {
            const int c = i * 4 + w;
            const int r = c * 8 + r8;              // d row 0..63
            const int s = sl ^ (r & 7);
            gld16(vtb + (size_t)r * SEQ + j0 + s * 8, Vb + c * 512);
        }
        #pragma unroll
        for (int q = 0; q < 5; ++q)
            #pragma unroll
            for (int reg = 0; reg < 4; ++reg) {
                const int cc2 = q * 16 + lo - g4 - reg;
                if (cc2 >= 0 && cc2 < 64)
                    T1c[(w16 + g4 + reg) * 68 + cc2] = f2bf(z1[q][reg]);
            }
        f32x4 accS[4];
        #pragma unroll
        for (int ct = 0; ct < 4; ++ct) {
            const bh8 kb0 = ldsfrag(Kb, ct * 16 + lo, slotA);
            const bh8 kb1 = ldsfrag(Kb, ct * 16 + lo, 4 + slotA);
            f32x4 z = {};
            z = __builtin_amdgcn_mfma_f32_16x16x32_bf16(qa0, kb0, z, 0, 0, 0);
            accS[ct] = __builtin_amdgcn_mfma_f32_16x16x32_bf16(qa1, kb1, z, 0, 0, 0);
        }
        float maskadd[4];
        #pragma unroll
        for (int ct = 0; ct < 4; ++ct)
            maskadd[ct] = -1e6f * (1.f - mrw[j0 + ct * 16 + lo]);
        __syncthreads();   // B3: posq staged, T1c visible

        #pragma unroll
        for (int q = 0; q < 5; ++q) {
            const int u2 = (3 - w + q) * 16 + lo;  // [48-w16, 128-w16)
            const bh8 pq0 = ldsfrag(POS, u2, slotA);
            const bh8 pq1 = ldsfrag(POS, u2, 4 + slotA);
            f32x4 z = {};
            z = __builtin_amdgcn_mfma_f32_16x16x32_bf16(ka0, pq0, z, 0, 0, 0);
            z = __builtin_amdgcn_mfma_f32_16x16x32_bf16(ka1, pq1, z, 0, 0, 0);
            #pragma unroll
            for (int reg = 0; reg < 4; ++reg) {
                const int il2 = q * 16 + lo + g4 + reg - 15;
                if (il2 >= 0 && il2 < 64)
                    T2c[(w16 + g4 + reg) * 68 + il2] = f2bf(z[reg]);
            }
        }
        __syncthreads();   // B4: T2c visible; V^T staged; POS dead

        float corr[4];
        char* pbase = (char*)POS + w * 2048;
        #pragma unroll
        for (int reg = 0; reg < 4; ++reg) {
            const int il = w16 + g4 + reg;
            const int gi = i0 + il;
            float s[4], rmax = -1e30f;
            #pragma unroll
            for (int ct = 0; ct < 4; ++ct) {
                const int jl = ct * 16 + lo;
                float v = accS[ct][reg];
                if (gi >= 1 && (j0 + jl) >= 1)
                    v += b2f(T1c[il * 68 + 63 - jl]) + b2f(T2c[jl * 68 + il]);
                v += maskadd[ct];
                s[ct] = v;
                rmax = fmaxf(rmax, v);
            }
            rmax = fmaxf(rmax, __shfl_xor(rmax, 1));
            rmax = fmaxf(rmax, __shfl_xor(rmax, 2));
            rmax = fmaxf(rmax, __shfl_xor(rmax, 4));
            rmax = fmaxf(rmax, __shfl_xor(rmax, 8));
            const float mnew = fmaxf(mrow[reg], rmax);
            const float cc   = __expf(mrow[reg] - mnew);
            float psum = 0.f;
            const int prow = g4 + reg;
            #pragma unroll
            for (int ct = 0; ct < 4; ++ct) {
                const float p = __expf(s[ct] - mnew);
                psum += p;
                *(ushort*)(pbase + prow * 128 + ((((ct * 16 + lo) * 2)) ^ ((prow & 7) * 16))) = f2bf(p);
            }
            psum += __shfl_xor(psum, 1);
            psum += __shfl_xor(psum, 2);
            psum += __shfl_xor(psum, 4);
            psum += __shfl_xor(psum, 8);
            lrow[reg] = lrow[reg] * cc + psum;
            mrow[reg] = mnew;
            corr[reg] = cc;
        }

        {
            const bh8 pa0 = *(const bh8*)(pbase + lo * 128 + ((slotA << 4) ^ ((lo & 7) * 16)));
            const bh8 pa1 = *(const bh8*)(pbase + lo * 128 + (((4 + slotA) << 4) ^ ((lo & 7) * 16)));
            #pragma unroll
            for (int dt = 0; dt < 4; ++dt) {
                const bh8 vb0 = ldsfrag(Vb, dt * 16 + lo, slotA);
                const bh8 vb1 = ldsfrag(Vb, dt * 16 + lo, 4 + slotA);
                f32x4 a = accPV[dt];
                #pragma unroll
                for (int reg = 0; reg < 4; ++reg) a[reg] *= corr[reg];
                a = __builtin_amdgcn_mfma_f32_16x16x32_bf16(pa0, vb0, a, 0, 0, 0);
                accPV[dt] = __builtin_amdgcn_mfma_f32_16x16x32_bf16(pa1, vb1, a, 0, 0, 0);
            }
        }
        __syncthreads();   // B5

        } else {
        // ================= CLAMPED CHUNK (rank-1 bias from cdv) =============
        const float* Dp = clamp0 ? D0p : D1p;
        float Dvv[4];
        #pragma unroll
        for (int ct = 0; ct < 4; ++ct)
            Dvv[ct] = Dp[j0 + ct * 16 + lo];
        float maskadd[4];
        #pragma unroll
        for (int ct = 0; ct < 4; ++ct)
            maskadd[ct] = -1e6f * (1.f - mrw[j0 + ct * 16 + lo]);

        #pragma unroll
        for (int i = 0; i < 2; ++i) {
            const int c = i * 4 + w;
            const int r = c * 8 + r8;
            const int s = sl ^ (r & 7);
            gld16(khb + (size_t)(j0 + r) * 64 + s * 8, Kb + c * 512);
            gld16(vtb + (size_t)r * SEQ + j0 + s * 8, Vb + c * 512);
        }
        __syncthreads();   // CB1

        f32x4 accS[4];
        #pragma unroll
        for (int ct = 0; ct < 4; ++ct) {
            const bh8 kb0 = ldsfrag(Kb, ct * 16 + lo, slotA);
            const bh8 kb1 = ldsfrag(Kb, ct * 16 + lo, 4 + slotA);
            f32x4 z = {};
            z = __builtin_amdgcn_mfma_f32_16x16x32_bf16(qa0, kb0, z, 0, 0, 0);
            accS[ct] = __builtin_amdgcn_mfma_f32_16x16x32_bf16(qa1, kb1, z, 0, 0, 0);
        }

        float corr[4];
        char* pbase = (char*)POS + w * 2048;
        #pragma unroll
        for (int reg = 0; reg < 4; ++reg) {
            const int il = w16 + g4 + reg;
            const int gi = i0 + il;
            const float Cvv = clamp0 ? C0r[reg] : C1r[reg];
            float s[4], rmax = -1e30f;
            #pragma unroll
            for (int ct = 0; ct < 4; ++ct) {
                const int jl = ct * 16 + lo;
                float v = accS[ct][reg];
                if (gi >= 1 && (j0 + jl) >= 1)
                    v += Cvv + Dvv[ct];
                v += maskadd[ct];
                s[ct] = v;
                rmax = fmaxf(rmax, v);
            }
            rmax = fmaxf(rmax, __shfl_xor(rmax, 1));
            rmax = fmaxf(rmax, __shfl_xor(rmax, 2));
            rmax = fmaxf(rmax, __shfl_xor(rmax, 4));
            rmax = fmaxf(rmax, __shfl_xor(rmax, 8));
            const float mnew = fmaxf(mrow[reg], rmax);
            const float cc   = __expf(mrow[reg] - mnew);
            float psum = 0.f;
            const int prow = g4 + reg;
            #pragma unroll
            for (int ct = 0; ct < 4; ++ct) {
                const float p = __expf(s[ct] - mnew);
                psum += p;
                *(ushort*)(pbase + prow * 128 + ((((ct * 16 + lo) * 2)) ^ ((prow & 7) * 16))) = f2bf(p);
            }
            psum += __shfl_xor(psum, 1);
            psum += __shfl_xor(psum, 2);
            psum += __shfl_xor(psum, 4);
            psum += __shfl_xor(psum, 8);
            lrow[reg] = lrow[reg] * cc + psum;
            mrow[reg] = mnew;
            corr[reg] = cc;
        }

        {
            const bh8 pa0 = *(const bh8*)(pbase + lo * 128 + ((slotA << 4) ^ ((lo & 7) * 16)));
            const bh8 pa1 = *(const bh8*)(pbase + lo * 128 + (((4 + slotA) << 4) ^ ((lo & 7) * 16)));
            #pragma unroll
            for (int dt = 0; dt < 4; ++dt) {
                const bh8 vb0 = ldsfrag(Vb, dt * 16 + lo, slotA);
                const bh8 vb1 = ldsfrag(Vb, dt * 16 + lo, 4 + slotA);
                f32x4 a = accPV[dt];
                #pragma unroll
                for (int reg = 0; reg < 4; ++reg) a[reg] *= corr[reg];
                a = __builtin_amdgcn_mfma_f32_16x16x32_bf16(pa0, vb0, a, 0, 0, 0);
                accPV[dt] = __builtin_amdgcn_mfma_f32_16x16x32_bf16(pa1, vb1, a, 0, 0, 0);
            }
        }
        __syncthreads();   // CB2
        }
    }

    #pragma unroll
    for (int reg = 0; reg < 4; ++reg) {
        const int i = i0 + w16 + g4 + reg;
        const float inv = 1.f / lrow[reg];
        #pragma unroll
        for (int dt = 0; dt < 4; ++dt)
            attn[((size_t)b * SEQ + i) * DMODEL + n * 64 + dt * 16 + lo] =
                accPV[dt][reg] * inv;
    }
}

// ---------------------------------------------------------------------------
// Residual + LayerNorm, in-place on attn buffer.
// ---------------------------------------------------------------------------
__global__ __launch_bounds__(256) void resid_ln(
    float* __restrict__ attn, const float* __restrict__ query,
    const float* __restrict__ gamma, const float* __restrict__ beta)
{
    const int b = blockIdx.y;
    const int i = blockIdx.x;
    const size_t base = ((size_t)b * SEQ + i) * DMODEL;
    const int tid = threadIdx.x;

    float x[3];
    #pragma unroll
    for (int s = 0; s < 3; ++s) x[s] = attn[base + s * 256 + tid];

    float sum = x[0] + x[1] + x[2];
    float sq  = x[0]*x[0] + x[1]*x[1] + x[2]*x[2];
    #pragma unroll
    for (int off = 32; off; off >>= 1) {
        sum += __shfl_xor(sum, off);
        sq  += __shfl_xor(sq, off);
    }
    __shared__ float red[2][4];
    const int w = tid >> 6;
    if ((tid & 63) == 0) { red[0][w] = sum; red[1][w] = sq; }
    __syncthreads();
    sum = red[0][0] + red[0][1] + red[0][2] + red[0][3];
    sq  = red[1][0] + red[1][1] + red[1][2] + red[1][3];

    const float mu  = sum * (1.f / DMODEL);
    const float var = sq * (1.f / DMODEL) - mu * mu;
    const float inv = rsqrtf(var + 1e-5f);

    #pragma unroll
    for (int s = 0; s < 3; ++s) {
        const int c = s * 256 + tid;
        attn[base + c] = query[base + c] + (x[s] - mu) * inv * gamma[c] + beta[c];
    }
}

// ---------------------------------------------------------------------------
extern "C" void kernel_launch(void* const* d_in, const int* in_sizes, int n_in,
                              void* d_out, int out_size, void* d_ws, size_t ws_size,
                              hipStream_t stream)
{
    const float* query = (const float*)d_in[0];
    const float* mask  = (const float*)d_in[1];
    const float* pke   = (const float*)d_in[2];
    const float* pqe   = (const float*)d_in[3];
    const float* Wq    = (const float*)d_in[4];
    const float* bq    = (const float*)d_in[5];
    const float* Wk    = (const float*)d_in[6];
    const float* Wv    = (const float*)d_in[7];
    const float* bv    = (const float*)d_in[8];
    const float* Wpq   = (const float*)d_in[9];
    const float* bpq   = (const float*)d_in[10];
    const float* Wpk   = (const float*)d_in[11];
    const float* rwb   = (const float*)d_in[12];
    const float* gamma = (const float*)d_in[13];
    const float* beta  = (const float*)d_in[14];

    float* out = (float*)d_out;

    const int Q_N  = NB * SEQ * DMODEL;
    const int P_N  = SPAN2 * DMODEL;
    const int W_N  = DMODEL * DMODEL;
    const size_t QKV_ELEMS = (size_t)NB * NHEAD * SEQ * 64;
    const size_t POS_ELEMS = (size_t)NHEAD * SPAN2 * 64;

    ushort* xb   = (ushort*)d_ws;
    ushort* pkeb = xb   + Q_N;
    ushort* pqeb = pkeb + P_N;
    ushort* wqb  = pqeb + P_N;
    ushort* wkb  = wqb  + W_N;
    ushort* wvb  = wkb  + W_N;
    ushort* wpqb = wvb  + W_N;
    ushort* wpkb = wpqb + W_N;
    ushort* qh   = wpkb + W_N;
    ushort* kh   = qh   + QKV_ELEMS;
    ushort* vht  = kh   + QKV_ELEMS;
    ushort* pkp  = vht  + QKV_ELEMS;
    ushort* pqp  = pkp  + POS_ELEMS;
    float*  cdv  = (float*)(pqp + POS_ELEMS);   // [4][24][2048] f32

    dim3 blk(256);

    CvtArgs ca;
    ca.src[0] = query; ca.dst[0] = xb;   ca.n[0] = Q_N;
    ca.src[1] = pke;   ca.dst[1] = pkeb; ca.n[1] = P_N;
    ca.src[2] = pqe;   ca.dst[2] = pqeb; ca.n[2] = P_N;
    ca.src[3] = Wq;    ca.dst[3] = wqb;  ca.n[3] = W_N;
    ca.src[4] = Wk;    ca.dst[4] = wkb;  ca.n[4] = W_N;
    ca.src[5] = Wv;    ca.dst[5] = wvb;  ca.n[5] = W_N;
    ca.src[6] = Wpq;   ca.dst[6] = wpqb; ca.n[6] = W_N;
    ca.src[7] = Wpk;   ca.dst[7] = wpkb; ca.n[7] = W_N;
    cvt_bf16<<<dim3((Q_N / 8 + 255) / 256, 8), blk, 0, stream>>>(ca);

    // merged projections (64-row QKV tiles -> grid 768 = 3/CU exact)
    proj_qkv<<<dim3(NB * SEQ / 64, NHEAD), blk, 0, stream>>>(
        xb, wqb, wkb, wvb, bq, rwb, bv, qh, kh, vht);
    proj_pos<<<dim3(SPAN2 / 32, NHEAD), blk, 0, stream>>>(
        pkeb, pqeb, wpkb, wpqb, bpq, pkp, pqp);

    // clamp-edge C/D vectors
    cd_vec<<<dim3(SEQ / 32, NB * NHEAD), blk, 0, stream>>>(
        qh, kh, pkp, pqp, cdv);

    // fused attention (v10 banded + slim clamped path) -> d_out
    attn_mfma10<<<dim3(NB * NHEAD * (SEQ / 64)), blk, 0, stream>>>(
        qh, kh, vht, pkp, pqp, mask, cdv, out);

    // residual + LN in-place
    resid_ln<<<dim3(SEQ, NB), blk, 0, stream>>>(out, query, gamma, beta);
}